// Round 1
// baseline (428.936 us; speedup 1.0000x reference)
//
#include <hip/hip_runtime.h>

// region_pooling: bilinear grid-sample + mean over points.
// feature_map: [B=8, HW=4096, C=1024] fp32 (H=W=64)
// point_coords: [B=8, M=32, P=512, 2] fp32, (y_norm, x_norm) in [0,1]
// out: [B, M, 1, C] fp32 = mean_p bilinear_sample(fm[b], coords[b,m,p])

#define NB 8
#define NM 32
#define NP 512
#define NC 1024
#define NH 64
#define NHW 4096

// One block per (b, m). 256 threads; thread t owns channels [4t, 4t+4).
// Stage per-point (row offsets, bilinear weights) in LDS, then gather-accumulate.
__global__ __launch_bounds__(256) void region_pool_direct(
    const float* __restrict__ fm,
    const float* __restrict__ pc,
    float* __restrict__ out)
{
    __shared__ int4   sIdx[NP];  // 4 row offsets (in floats, i.e. row*1024)
    __shared__ float4 sW[NP];    // 4 bilinear weights

    const int bid = blockIdx.x;          // bid = b*NM + m
    const int b   = bid >> 5;
    const int tid = threadIdx.x;

    // ---- stage point metadata into LDS (coalesced float2 coord loads) ----
    const float2* pc2 = (const float2*)(pc + (size_t)bid * NP * 2);
    for (int p = tid; p < NP; p += 256) {
        float2 c = pc2[p];               // (y_norm, x_norm)
        float y = c.x * 63.0f;
        float x = c.y * 63.0f;
        float x0f = floorf(x);
        float y0f = floorf(y);
        float wx = x - x0f;
        float wy = y - y0f;
        int ix0 = min(max((int)x0f, 0), 63);
        int ix1 = min(ix0 + 1, 63);
        int iy0 = min(max((int)y0f, 0), 63);
        int iy1 = min(iy0 + 1, 63);
        int r00 = (iy0 * NH + ix0) << 10;   // * NC
        int r01 = (iy0 * NH + ix1) << 10;
        int r10 = (iy1 * NH + ix0) << 10;
        int r11 = (iy1 * NH + ix1) << 10;
        sIdx[p] = make_int4(r00, r01, r10, r11);
        float wx1 = 1.0f - wx, wy1 = 1.0f - wy;
        sW[p] = make_float4(wx1 * wy1, wx * wy1, wx1 * wy, wx * wy);
    }
    __syncthreads();

    // ---- gather-accumulate over the 512 points ----
    const float* Fb = fm + (size_t)b * (NHW * NC) + tid * 4;
    float4 acc = make_float4(0.f, 0.f, 0.f, 0.f);

#pragma unroll 4
    for (int p = 0; p < NP; ++p) {
        int4   off = sIdx[p];
        float4 w   = sW[p];
        float4 f00 = *(const float4*)(Fb + off.x);
        float4 f01 = *(const float4*)(Fb + off.y);
        float4 f10 = *(const float4*)(Fb + off.z);
        float4 f11 = *(const float4*)(Fb + off.w);
        acc.x = fmaf(w.x, f00.x, acc.x);
        acc.y = fmaf(w.x, f00.y, acc.y);
        acc.z = fmaf(w.x, f00.z, acc.z);
        acc.w = fmaf(w.x, f00.w, acc.w);
        acc.x = fmaf(w.y, f01.x, acc.x);
        acc.y = fmaf(w.y, f01.y, acc.y);
        acc.z = fmaf(w.y, f01.z, acc.z);
        acc.w = fmaf(w.y, f01.w, acc.w);
        acc.x = fmaf(w.z, f10.x, acc.x);
        acc.y = fmaf(w.z, f10.y, acc.y);
        acc.z = fmaf(w.z, f10.z, acc.z);
        acc.w = fmaf(w.z, f10.w, acc.w);
        acc.x = fmaf(w.w, f11.x, acc.x);
        acc.y = fmaf(w.w, f11.y, acc.y);
        acc.z = fmaf(w.w, f11.z, acc.z);
        acc.w = fmaf(w.w, f11.w, acc.w);
    }

    const float inv = 1.0f / (float)NP;
    float4 res = make_float4(acc.x * inv, acc.y * inv, acc.z * inv, acc.w * inv);
    ((float4*)(out + (size_t)bid * NC))[tid] = res;
}

extern "C" void kernel_launch(void* const* d_in, const int* in_sizes, int n_in,
                              void* d_out, int out_size, void* d_ws, size_t ws_size,
                              hipStream_t stream) {
    const float* fm = (const float*)d_in[0];   // [8, 4096, 1024]
    const float* pc = (const float*)d_in[1];   // [8, 32, 512, 2]
    float* out = (float*)d_out;                // [8, 32, 1, 1024]
    region_pool_direct<<<NB * NM, 256, 0, stream>>>(fm, pc, out);
}

// Round 2
// 243.109 us; speedup vs baseline: 1.7644x; 1.7644x over previous
//
#include <hip/hip_runtime.h>

// region_pooling via scatter + dense GEMM.
// feature_map F: [B=8, HW=4096, C=1024] fp32 (H=W=64)
// point_coords: [B=8, M=32, P=512, 2] fp32 (y_norm, x_norm)
// out: [B, M, 1, C] = (1/P) * W_b^T @ F_b, where W[b][hw][m] accumulates
// bilinear corner weights of all points of region m that touch cell hw.

#define NB 8
#define NM 32
#define NP 512
#define NC 1024
#define NH 64
#define NHW 4096

#define KC   256                  // hw per k-chunk
#define NKC  (NHW / KC)           // 16 k-chunks
#define CT   256                  // channels per block
#define NCT  (NC / CT)            // 4 c-tiles

// ---- Phase 1: scatter bilinear weights into W[b][hw][m] (pre-zeroed) ----
__global__ __launch_bounds__(256) void scatter_w(
    const float* __restrict__ pc, float* __restrict__ W)
{
    int idx = blockIdx.x * 256 + threadIdx.x;   // [0, B*M*P)
    int bm  = idx >> 9;                         // b*NM + m
    int m   = bm & (NM - 1);
    int b   = bm >> 5;

    float2 c = ((const float2*)pc)[idx];
    float y = c.x * 63.0f;
    float x = c.y * 63.0f;
    float x0f = floorf(x), y0f = floorf(y);
    float wx = x - x0f, wy = y - y0f;
    int ix0 = min(max((int)x0f, 0), 63);
    int ix1 = min(ix0 + 1, 63);
    int iy0 = min(max((int)y0f, 0), 63);
    int iy1 = min(iy0 + 1, 63);
    float wx1 = 1.0f - wx, wy1 = 1.0f - wy;
    const float s = 1.0f / (float)NP;           // fold the mean here

    float* Wb = W + (size_t)b * (NHW * NM) + m;
    atomicAdd(Wb + ((iy0 * NH + ix0) * NM), wx1 * wy1 * s);
    atomicAdd(Wb + ((iy0 * NH + ix1) * NM), wx  * wy1 * s);
    atomicAdd(Wb + ((iy1 * NH + ix0) * NM), wx1 * wy  * s);
    atomicAdd(Wb + ((iy1 * NH + ix1) * NM), wx  * wy  * s);
}

// ---- Phase 2: Out[b][m][c] += sum_hw W[b][hw][m] * F[b][hw][c] ----
// Thread owns channel c, all 32 m accumulators. W reads are wave-uniform
// (s_load + v_fma with SGPR operand). Out pre-zeroed; k-chunks atomicAdd.
__global__ __launch_bounds__(256) void wgemm(
    const float* __restrict__ W, const float* __restrict__ F,
    float* __restrict__ out)
{
    const int kc = blockIdx.x;                  // 16 k-chunks of KC
    const int ct = blockIdx.y;                  // 4 c-tiles of CT
    const int b  = blockIdx.z;
    const int c  = ct * CT + threadIdx.x;
    const int hw0 = kc * KC;

    const float* Wb = W + ((size_t)b * NHW + hw0) * NM;
    const float* Fb = F + ((size_t)b * NHW + hw0) * NC + c;

    float acc[NM];
#pragma unroll
    for (int m = 0; m < NM; ++m) acc[m] = 0.0f;

#pragma unroll 4
    for (int i = 0; i < KC; ++i) {
        float f = Fb[(size_t)i * NC];
#pragma unroll
        for (int m = 0; m < NM; ++m)
            acc[m] = fmaf(Wb[i * NM + m], f, acc[m]);
    }

    float* ob = out + (size_t)b * (NM * NC) + c;
#pragma unroll
    for (int m = 0; m < NM; ++m)
        atomicAdd(ob + (size_t)m * NC, acc[m]);
}

// ---- Fallback (ws too small): round-1 direct gather ----
__global__ __launch_bounds__(256) void region_pool_direct(
    const float* __restrict__ fm, const float* __restrict__ pc,
    float* __restrict__ out)
{
    __shared__ int4   sIdx[NP];
    __shared__ float4 sW[NP];
    const int bid = blockIdx.x;
    const int b   = bid >> 5;
    const int tid = threadIdx.x;
    const float2* pc2 = (const float2*)(pc + (size_t)bid * NP * 2);
    for (int p = tid; p < NP; p += 256) {
        float2 c = pc2[p];
        float y = c.x * 63.0f, x = c.y * 63.0f;
        float x0f = floorf(x), y0f = floorf(y);
        float wx = x - x0f, wy = y - y0f;
        int ix0 = min(max((int)x0f, 0), 63);
        int ix1 = min(ix0 + 1, 63);
        int iy0 = min(max((int)y0f, 0), 63);
        int iy1 = min(iy0 + 1, 63);
        sIdx[p] = make_int4((iy0 * NH + ix0) << 10, (iy0 * NH + ix1) << 10,
                            (iy1 * NH + ix0) << 10, (iy1 * NH + ix1) << 10);
        float wx1 = 1.0f - wx, wy1 = 1.0f - wy;
        sW[p] = make_float4(wx1 * wy1, wx * wy1, wx1 * wy, wx * wy);
    }
    __syncthreads();
    const float* Fb = fm + (size_t)b * (NHW * NC) + tid * 4;
    float4 acc = make_float4(0.f, 0.f, 0.f, 0.f);
#pragma unroll 4
    for (int p = 0; p < NP; ++p) {
        int4 off = sIdx[p]; float4 w = sW[p];
        float4 f00 = *(const float4*)(Fb + off.x);
        float4 f01 = *(const float4*)(Fb + off.y);
        float4 f10 = *(const float4*)(Fb + off.z);
        float4 f11 = *(const float4*)(Fb + off.w);
        acc.x = fmaf(w.x, f00.x, fmaf(w.y, f01.x, fmaf(w.z, f10.x, fmaf(w.w, f11.x, acc.x))));
        acc.y = fmaf(w.x, f00.y, fmaf(w.y, f01.y, fmaf(w.z, f10.y, fmaf(w.w, f11.y, acc.y))));
        acc.z = fmaf(w.x, f00.z, fmaf(w.y, f01.z, fmaf(w.z, f10.z, fmaf(w.w, f11.z, acc.z))));
        acc.w = fmaf(w.x, f00.w, fmaf(w.y, f01.w, fmaf(w.z, f10.w, fmaf(w.w, f11.w, acc.w))));
    }
    const float inv = 1.0f / (float)NP;
    ((float4*)(out + (size_t)bid * NC))[tid] =
        make_float4(acc.x * inv, acc.y * inv, acc.z * inv, acc.w * inv);
}

extern "C" void kernel_launch(void* const* d_in, const int* in_sizes, int n_in,
                              void* d_out, int out_size, void* d_ws, size_t ws_size,
                              hipStream_t stream) {
    const float* fm = (const float*)d_in[0];   // [8, 4096, 1024]
    const float* pc = (const float*)d_in[1];   // [8, 32, 512, 2]
    float* out = (float*)d_out;                // [8, 32, 1, 1024]

    const size_t wbytes = (size_t)NB * NHW * NM * sizeof(float);  // 4 MB
    if (ws_size >= wbytes) {
        float* W = (float*)d_ws;
        hipMemsetAsync(W, 0, wbytes, stream);
        hipMemsetAsync(out, 0, (size_t)out_size * sizeof(float), stream);
        scatter_w<<<(NB * NM * NP) / 256, 256, 0, stream>>>(pc, W);
        dim3 grid(NKC, NCT, NB);
        wgemm<<<grid, CT, 0, stream>>>(W, fm, out);
    } else {
        region_pool_direct<<<NB * NM, 256, 0, stream>>>(fm, pc, out);
    }
}